// Round 1
// baseline (503.188 us; speedup 1.0000x reference)
//
#include <hip/hip_runtime.h>
#include <hip/hip_bf16.h>

// DecoderRNN: B=64 batch, S=32 caption len, T=31 decode steps, E=D=512, V=10000
// Pipeline: k_wlstm -> k_prep -> k_xproj -> k_rec (persistent, grid-synced) -> k_cls

typedef __attribute__((ext_vector_type(4))) float f32x4;
typedef __attribute__((ext_vector_type(8))) short short8;

#define BB 64
#define SS 32
#define TT 31
#define EE 512
#define VV 10000

__device__ __forceinline__ float sigf(float x){ return 1.0f/(1.0f + __expf(-x)); }
__device__ __forceinline__ float tanh_(float x){
  x = fminf(15.f, fmaxf(-15.f, x));
  float e = __expf(2.f*x);
  return (e-1.f)/(e+1.f);
}

// ---------------------------------------------------------------------------
// Kernel 1: hidden-size-1 "w" LSTM for all 64 rows + dl output + barrier init.
// grid 64 (one WG per batch row), block 256 (4 waves).
// ---------------------------------------------------------------------------
__global__ __launch_bounds__(256) void k_wlstm(
    const float* __restrict__ enc, const int* __restrict__ caplen,
    const float* __restrict__ wwih, const float* __restrict__ wwhh,
    const float* __restrict__ wbih, const float* __restrict__ wbhh,
    const float* __restrict__ ihw, const float* __restrict__ ihb,
    const float* __restrict__ icw, const float* __restrict__ icb,
    float* __restrict__ wgt, unsigned* __restrict__ barr,
    float* __restrict__ dl_out)
{
  int b = blockIdx.x;
  int w = threadIdx.x >> 6, lane = threadIdx.x & 63;
  __shared__ float sv[6];   // ew[0..3], wh0, wc0

  // wave w: dot(enc[b], w_wih[w])
  float p = 0.f;
  for (int k = lane; k < EE; k += 64) p += enc[b*EE + k] * wwih[w*EE + k];
  #pragma unroll
  for (int off = 32; off; off >>= 1) p += __shfl_down(p, off, 64);
  if (lane == 0) sv[w] = p;

  if (w < 2){
    const float* iw = (w == 0) ? ihw : icw;
    float q = 0.f;
    for (int k = lane; k < EE; k += 64) q += enc[b*EE + k] * iw[k];
    #pragma unroll
    for (int off = 32; off; off >>= 1) q += __shfl_down(q, off, 64);
    if (lane == 0) sv[4 + w] = q + ((w == 0) ? ihb[0] : icb[0]);
  }
  __syncthreads();

  if (threadIdx.x == 0){
    float wh = sv[4], wc = sv[5];
    int dl = caplen[b] - 1;
    for (int t = 0; t < TT; t++){
      float gi = sv[0] + wh*wwhh[0] + wbih[0] + wbhh[0];
      float gf = sv[1] + wh*wwhh[1] + wbih[1] + wbhh[1];
      float gg = sv[2] + wh*wwhh[2] + wbih[2] + wbhh[2];
      float go = sv[3] + wh*wwhh[3] + wbih[3] + wbhh[3];
      float wc2 = sigf(gf)*wc + sigf(gi)*tanh_(gg);
      float wh2 = sigf(go)*tanh_(wc2);
      float m = (dl > t) ? 1.f : 0.f;
      wgt[b*TT + t] = sigf(wh2) * m;
      if (dl > t){ wh = wh2; wc = wc2; }
    }
    dl_out[b] = (float)dl;
  }
  // zero the 4 per-group barrier counters (stride 32 u32 = 128 B)
  if (b == 0 && threadIdx.x < 128) barr[threadIdx.x] = 0;
}

// ---------------------------------------------------------------------------
// Kernel 2: bf16 conversions + gathered A-matrix for the x-projection + h0.
// ---------------------------------------------------------------------------
__global__ void k_prep(
    const float* __restrict__ clsw, const float* __restrict__ dwih,
    const float* __restrict__ dwhh, const float* __restrict__ emb,
    const int* __restrict__ cap, const float* __restrict__ enc,
    __hip_bfloat16* __restrict__ clsbf, __hip_bfloat16* __restrict__ wihbf,
    __hip_bfloat16* __restrict__ whhbf, __hip_bfloat16* __restrict__ xa,
    __hip_bfloat16* __restrict__ h0)
{
  const int c1 = 5120000;              // cls_w      [10000][512]
  const int c2 = c1 + 2097152;         // dec_wih    [2048][1024]
  const int c3 = c2 + 1048576;         // dec_whh    [2048][512]
  const int c4 = c3 + 2031616;         // Xa         [1984][1024]  (row r = t*64+b)
  const int c5 = c4 + 32768;           // h0         [64][512]
  for (int i = blockIdx.x*blockDim.x + threadIdx.x; i < c5; i += gridDim.x*blockDim.x){
    float v; __hip_bfloat16* dst;
    if (i < c1){ v = clsw[i]; dst = clsbf + i; }
    else if (i < c2){ int j = i - c1; v = dwih[j]; dst = wihbf + j; }
    else if (i < c3){ int j = i - c2; v = dwhh[j]; dst = whhbf + j; }
    else if (i < c4){
      int j = i - c3; int r = j >> 10, k = j & 1023, t = r >> 6, b = r & 63;
      v = (k < 512) ? emb[(size_t)cap[b*SS + t]*EE + k] : enc[b*EE + (k - 512)];
      dst = xa + j;
    } else { int j = i - c4; v = enc[j]; dst = h0 + j; }
    *dst = __float2bfloat16(v);
  }
}

// ---------------------------------------------------------------------------
// Kernel 3: x-projection GEMM: Xp[r][n] = Xa[r] . wih[n] + bih[n] + bhh[n]
// M=1984 (r = t*64+b), N=2048, K=1024. Wave = 64x64 tile, WG = 64x256.
// grid (8, 31), block 256.
// ---------------------------------------------------------------------------
__global__ __launch_bounds__(256) void k_xproj(
    const __hip_bfloat16* __restrict__ xa, const __hip_bfloat16* __restrict__ wihbf,
    const float* __restrict__ bih, const float* __restrict__ bhh,
    float* __restrict__ xp)
{
  int bm = blockIdx.y;                 // 0..30
  int bn = blockIdx.x;                 // 0..7
  int w = threadIdx.x >> 6, lane = threadIdx.x & 63;
  int col = lane & 15, kg = lane >> 4;
  int m0 = bm*64;
  int n0 = bn*256 + w*64;

  f32x4 acc[4][4] = {};
  for (int kk = 0; kk < 32; kk++){
    short8 a[4], bfr[4];
    #pragma unroll
    for (int i = 0; i < 4; i++){
      a[i]   = *(const short8*)(xa    + (size_t)(m0 + i*16 + col)*1024 + kk*32 + kg*8);
      bfr[i] = *(const short8*)(wihbf + (size_t)(n0 + i*16 + col)*1024 + kk*32 + kg*8);
    }
    #pragma unroll
    for (int mt = 0; mt < 4; mt++)
      #pragma unroll
      for (int nt = 0; nt < 4; nt++)
        acc[mt][nt] = __builtin_amdgcn_mfma_f32_16x16x32_bf16(a[mt], bfr[nt], acc[mt][nt], 0, 0, 0);
  }
  float badd[4]; int ncol[4];
  #pragma unroll
  for (int nt = 0; nt < 4; nt++){ int n = n0 + nt*16 + col; ncol[nt] = n; badd[nt] = bih[n] + bhh[n]; }
  #pragma unroll
  for (int mt = 0; mt < 4; mt++)
    #pragma unroll
    for (int rg = 0; rg < 4; rg++){
      int r = m0 + mt*16 + 4*kg + rg;
      #pragma unroll
      for (int nt = 0; nt < 4; nt++)
        xp[(size_t)r*2048 + ncol[nt]] = acc[mt][nt][rg] + badd[nt];
    }
}

// ---------------------------------------------------------------------------
// Kernel 4: persistent recurrence. 4 batch-groups (16 rows) x 32 slice-waves
// (16 d-cols each). Whh slice (64 gate cols x K=512) held in 256 VGPRs for all
// 31 steps. One atomic barrier per group per step; h ping-pongs via L2.
// grid 128, block 64 (1 wave per WG; <=512 VGPR budget).
// ---------------------------------------------------------------------------
__global__ __launch_bounds__(64, 1) void k_rec(
    const __hip_bfloat16* __restrict__ whhbf,  // [2048][512]
    const float* __restrict__ xp,              // [T*64][2048]
    const float* __restrict__ enc,             // [64][512]
    const int* __restrict__ caplen,
    __hip_bfloat16* __restrict__ hbuf,         // [2][64][512] ping-pong
    __hip_bfloat16* __restrict__ hout,         // [64][T][512]
    unsigned* __restrict__ barr)               // 4 counters, 128 B apart
{
  const int wg = blockIdx.x;            // 0..127
  const int g = wg >> 5, s = wg & 31;   // group, slice
  const int lane = threadIdx.x;
  const int col = lane & 15, kg = lane >> 4;
  const int d0 = s*16;
  const int b0 = g*16;
  const int d = d0 + col;

  // persistent B fragments: Whh rows {512q + d0 + col}, all K=512
  short8 Bq[4][16];
  #pragma unroll
  for (int q = 0; q < 4; q++){
    const __hip_bfloat16* wrow = whhbf + (size_t)(q*512 + d0 + col)*512;
    #pragma unroll
    for (int kk = 0; kk < 16; kk++)
      Bq[q][kk] = *(const short8*)(wrow + kk*32 + kg*8);
  }

  // per-lane persistent state: 4 batch rows (b = b0 + 4*kg + rg), column d
  float hstate[4], cstate[4]; int dl[4];
  #pragma unroll
  for (int rg = 0; rg < 4; rg++){
    int b = b0 + 4*kg + rg;
    float e = enc[(size_t)b*EE + d];
    hstate[rg] = e; cstate[rg] = e;
    dl[rg] = caplen[b] - 1;
  }
  unsigned* cnt = barr + g*32;

  for (int t = 0; t < TT; t++){
    const __hip_bfloat16* hc = hbuf + (size_t)(t & 1)*(BB*EE);
    __hip_bfloat16*       hn = hbuf + (size_t)((t + 1) & 1)*(BB*EE);

    f32x4 acc[4] = {};
    #pragma unroll
    for (int kk = 0; kk < 16; kk++){
      short8 a = *(const short8*)(hc + (size_t)(b0 + col)*EE + kk*32 + kg*8);
      #pragma unroll
      for (int q = 0; q < 4; q++)
        acc[q] = __builtin_amdgcn_mfma_f32_16x16x32_bf16(a, Bq[q][kk], acc[q], 0, 0, 0);
    }

    #pragma unroll
    for (int rg = 0; rg < 4; rg++){
      int b = b0 + 4*kg + rg;
      const float* xprow = xp + (size_t)(t*BB + b)*2048;
      float gi = acc[0][rg] + xprow[0*512 + d];
      float gf = acc[1][rg] + xprow[1*512 + d];
      float gg = acc[2][rg] + xprow[2*512 + d];
      float go = acc[3][rg] + xprow[3*512 + d];
      float c2 = sigf(gf)*cstate[rg] + sigf(gi)*tanh_(gg);
      float h2 = sigf(go)*tanh_(c2);
      bool m = dl[rg] > t;
      cstate[rg] = m ? c2 : cstate[rg];
      hstate[rg] = m ? h2 : hstate[rg];
      hout[((size_t)b*TT + t)*EE + d] = __float2bfloat16(h2);     // fresh h2 for preds
      hn[(size_t)b*EE + d]            = __float2bfloat16(hstate[rg]);
    }

    if (t < TT - 1){
      __threadfence();                         // release h writes to L2
      if (lane == 0) atomicAdd(cnt, 1u);
      unsigned target = 32u*(unsigned)(t + 1); // monotone counter: no reset race
      while (__hip_atomic_load(cnt, __ATOMIC_ACQUIRE, __HIP_MEMORY_SCOPE_AGENT) < target)
        __builtin_amdgcn_s_sleep(1);
    }
  }
}

// ---------------------------------------------------------------------------
// Kernel 5: classifier GEMM fused with mask + weights broadcast.
// preds[r][v] = (H[r].cls_w[v] + cls_b[v]) * m(r); wout[r][v] = wgt[r].
// M=1984 (r=b*31+t), N=10000, K=512. Wave = 64x64, WG = 128x128.
// grid 16*79, block 256.
// ---------------------------------------------------------------------------
__global__ __launch_bounds__(256) void k_cls(
    const __hip_bfloat16* __restrict__ hbf,   // [1984][512]
    const __hip_bfloat16* __restrict__ wbf,   // [10000][512]
    const float* __restrict__ clsb,
    const float* __restrict__ wgt,            // [1984], ==0 iff masked
    float* __restrict__ preds, float* __restrict__ wout)
{
  int bid = blockIdx.x;
  int bn = bid % 79, bm = bid / 79;
  int w = threadIdx.x >> 6, lane = threadIdx.x & 63;
  int col = lane & 15, kg = lane >> 4;
  int m0 = bm*128 + (w >> 1)*64;
  int n0 = bn*128 + (w & 1)*64;
  if (m0 >= 1984) return;                     // whole wave OOB (no barriers used)

  int arow[4], brow[4];
  #pragma unroll
  for (int i = 0; i < 4; i++){
    arow[i] = min(m0 + i*16 + col, 1983);
    brow[i] = min(n0 + i*16 + col, 9999);
  }
  f32x4 acc[4][4] = {};
  for (int kk = 0; kk < 16; kk++){
    short8 a[4], b[4];
    #pragma unroll
    for (int i = 0; i < 4; i++){
      a[i] = *(const short8*)(hbf + (size_t)arow[i]*512 + kk*32 + kg*8);
      b[i] = *(const short8*)(wbf + (size_t)brow[i]*512 + kk*32 + kg*8);
    }
    #pragma unroll
    for (int mt = 0; mt < 4; mt++)
      #pragma unroll
      for (int nt = 0; nt < 4; nt++)
        acc[mt][nt] = __builtin_amdgcn_mfma_f32_16x16x32_bf16(a[mt], b[nt], acc[mt][nt], 0, 0, 0);
  }
  float cb[4]; int vcol[4]; bool vok[4];
  #pragma unroll
  for (int nt = 0; nt < 4; nt++){
    int v = n0 + nt*16 + col; vcol[nt] = v; vok[nt] = (v < VV);
    cb[nt] = vok[nt] ? clsb[v] : 0.f;
  }
  #pragma unroll
  for (int mt = 0; mt < 4; mt++)
    #pragma unroll
    for (int rg = 0; rg < 4; rg++){
      int r = m0 + mt*16 + 4*kg + rg;
      if (r >= 1984) continue;
      float wv = wgt[r];
      float mf = (wv > 0.f) ? 1.f : 0.f;      // sigmoid output: 0 only when masked
      size_t base = (size_t)r*VV;
      #pragma unroll
      for (int nt = 0; nt < 4; nt++){
        if (!vok[nt]) continue;
        preds[base + vcol[nt]] = (acc[mt][nt][rg] + cb[nt]) * mf;
        wout [base + vcol[nt]] = wv;
      }
    }
}

// ---------------------------------------------------------------------------
extern "C" void kernel_launch(void* const* d_in, const int* in_sizes, int n_in,
                              void* d_out, int out_size, void* d_ws, size_t ws_size,
                              hipStream_t stream) {
  const float* enc    = (const float*)d_in[0];
  const int*   cap    = (const int*)  d_in[1];
  const int*   caplen = (const int*)  d_in[2];
  const float* emb    = (const float*)d_in[3];
  const float* dwih   = (const float*)d_in[4];
  const float* dwhh   = (const float*)d_in[5];
  const float* dbih   = (const float*)d_in[6];
  const float* dbhh   = (const float*)d_in[7];
  const float* wwih   = (const float*)d_in[8];
  const float* wwhh   = (const float*)d_in[9];
  const float* wbih   = (const float*)d_in[10];
  const float* wbhh   = (const float*)d_in[11];
  const float* ihw    = (const float*)d_in[12];
  const float* ihb    = (const float*)d_in[13];
  const float* icw    = (const float*)d_in[14];
  const float* icb    = (const float*)d_in[15];
  const float* clsw   = (const float*)d_in[16];
  const float* clsb   = (const float*)d_in[17];

  float* preds  = (float*)d_out;                       // [64][31][10000]
  float* dl_out = preds + (size_t)BB*TT*VV;            // [64]
  float* wout   = dl_out + BB;                         // [64][31][10000]

  char* ws = (char*)d_ws;
  float*          wgt   = (float*)         (ws + 0);          // 1984 f32   (pad 8192)
  unsigned*       barr  = (unsigned*)      (ws + 8192);       // 128 u32    (pad 512)
  __hip_bfloat16* clsbf = (__hip_bfloat16*)(ws + 8704);       // 10,240,000 B
  __hip_bfloat16* wihbf = (__hip_bfloat16*)(ws + 10248704);   //  4,194,304 B
  __hip_bfloat16* whhbf = (__hip_bfloat16*)(ws + 14443008);   //  2,097,152 B
  __hip_bfloat16* xa    = (__hip_bfloat16*)(ws + 16540160);   //  4,063,232 B
  float*          xp    = (float*)         (ws + 20603392);   // 16,252,928 B
  __hip_bfloat16* hbuf  = (__hip_bfloat16*)(ws + 36856320);   //    131,072 B
  __hip_bfloat16* hout  = (__hip_bfloat16*)(ws + 36987392);   //  2,031,616 B
  // total ~39.0 MB of d_ws

  k_wlstm<<<BB, 256, 0, stream>>>(enc, caplen, wwih, wwhh, wbih, wbhh,
                                  ihw, ihb, icw, icb, wgt, barr, dl_out);
  k_prep <<<4096, 256, 0, stream>>>(clsw, dwih, dwhh, emb, cap, enc,
                                    clsbf, wihbf, whhbf, xa, hbuf);
  k_xproj<<<dim3(8, 31), 256, 0, stream>>>(xa, wihbf, dbih, dbhh, xp);
  k_rec  <<<128, 64, 0, stream>>>(whhbf, xp, enc, caplen, hbuf, hout, barr);
  k_cls  <<<16*79, 256, 0, stream>>>(hout, clsbf, clsb, wgt, preds, wout);
}

// Round 2
// 354.493 us; speedup vs baseline: 1.4195x; 1.4195x over previous
//
#include <hip/hip_runtime.h>
#include <hip/hip_bf16.h>

// DecoderRNN: B=64 batch, S=32 caption len, T=31 decode steps, E=D=512, V=10000
// Pipeline: k_wlstm -> k_prep -> k_xproj -> k_rec (persistent, grid-synced) -> k_cls

typedef __attribute__((ext_vector_type(4))) float f32x4;
typedef __attribute__((ext_vector_type(8))) short short8;

#define BB 64
#define SS 32
#define TT 31
#define EE 512
#define VV 10000

__device__ __forceinline__ float sigf(float x){ return 1.0f/(1.0f + __expf(-x)); }
__device__ __forceinline__ float tanh_(float x){
  x = fminf(15.f, fmaxf(-15.f, x));
  float e = __expf(2.f*x);
  return (e-1.f)/(e+1.f);
}
__device__ __forceinline__ unsigned short f2bf(float x){
  __hip_bfloat16 h = __float2bfloat16(x);
  return __builtin_bit_cast(unsigned short, h);
}

// ---------------------------------------------------------------------------
// Kernel 1: hidden-size-1 "w" LSTM for all 64 rows + dl output + barrier init.
// ---------------------------------------------------------------------------
__global__ __launch_bounds__(256) void k_wlstm(
    const float* __restrict__ enc, const int* __restrict__ caplen,
    const float* __restrict__ wwih, const float* __restrict__ wwhh,
    const float* __restrict__ wbih, const float* __restrict__ wbhh,
    const float* __restrict__ ihw, const float* __restrict__ ihb,
    const float* __restrict__ icw, const float* __restrict__ icb,
    float* __restrict__ wgt, unsigned* __restrict__ barr,
    float* __restrict__ dl_out)
{
  int b = blockIdx.x;
  int w = threadIdx.x >> 6, lane = threadIdx.x & 63;
  __shared__ float sv[6];   // ew[0..3], wh0, wc0

  float p = 0.f;
  for (int k = lane; k < EE; k += 64) p += enc[b*EE + k] * wwih[w*EE + k];
  #pragma unroll
  for (int off = 32; off; off >>= 1) p += __shfl_down(p, off, 64);
  if (lane == 0) sv[w] = p;

  if (w < 2){
    const float* iw = (w == 0) ? ihw : icw;
    float q = 0.f;
    for (int k = lane; k < EE; k += 64) q += enc[b*EE + k] * iw[k];
    #pragma unroll
    for (int off = 32; off; off >>= 1) q += __shfl_down(q, off, 64);
    if (lane == 0) sv[4 + w] = q + ((w == 0) ? ihb[0] : icb[0]);
  }
  __syncthreads();

  if (threadIdx.x == 0){
    float wh = sv[4], wc = sv[5];
    int dl = caplen[b] - 1;
    for (int t = 0; t < TT; t++){
      float gi = sv[0] + wh*wwhh[0] + wbih[0] + wbhh[0];
      float gf = sv[1] + wh*wwhh[1] + wbih[1] + wbhh[1];
      float gg = sv[2] + wh*wwhh[2] + wbih[2] + wbhh[2];
      float go = sv[3] + wh*wwhh[3] + wbih[3] + wbhh[3];
      float wc2 = sigf(gf)*wc + sigf(gi)*tanh_(gg);
      float wh2 = sigf(go)*tanh_(wc2);
      float m = (dl > t) ? 1.f : 0.f;
      wgt[b*TT + t] = sigf(wh2) * m;
      if (dl > t){ wh = wh2; wc = wc2; }
    }
    dl_out[b] = (float)dl;
  }
  if (b == 0 && threadIdx.x < 128) barr[threadIdx.x] = 0;
}

// ---------------------------------------------------------------------------
// Kernel 2: bf16 conversions + gathered A-matrix for the x-projection + h0.
// ---------------------------------------------------------------------------
__global__ void k_prep(
    const float* __restrict__ clsw, const float* __restrict__ dwih,
    const float* __restrict__ dwhh, const float* __restrict__ emb,
    const int* __restrict__ cap, const float* __restrict__ enc,
    __hip_bfloat16* __restrict__ clsbf, __hip_bfloat16* __restrict__ wihbf,
    __hip_bfloat16* __restrict__ whhbf, __hip_bfloat16* __restrict__ xa,
    __hip_bfloat16* __restrict__ h0)
{
  const int c1 = 5120000;              // cls_w      [10000][512]
  const int c2 = c1 + 2097152;         // dec_wih    [2048][1024]
  const int c3 = c2 + 1048576;         // dec_whh    [2048][512]
  const int c4 = c3 + 2031616;         // Xa         [1984][1024]  (row r = t*64+b)
  const int c5 = c4 + 32768;           // h0         [64][512]
  for (int i = blockIdx.x*blockDim.x + threadIdx.x; i < c5; i += gridDim.x*blockDim.x){
    float v; __hip_bfloat16* dst;
    if (i < c1){ v = clsw[i]; dst = clsbf + i; }
    else if (i < c2){ int j = i - c1; v = dwih[j]; dst = wihbf + j; }
    else if (i < c3){ int j = i - c2; v = dwhh[j]; dst = whhbf + j; }
    else if (i < c4){
      int j = i - c3; int r = j >> 10, k = j & 1023, t = r >> 6, b = r & 63;
      v = (k < 512) ? emb[(size_t)cap[b*SS + t]*EE + k] : enc[b*EE + (k - 512)];
      dst = xa + j;
    } else { int j = i - c4; v = enc[j]; dst = h0 + j; }
    *dst = __float2bfloat16(v);
  }
}

// ---------------------------------------------------------------------------
// Kernel 3: x-projection GEMM: Xp[r][n] = Xa[r] . wih[n] + bih[n] + bhh[n]
// ---------------------------------------------------------------------------
__global__ __launch_bounds__(256) void k_xproj(
    const __hip_bfloat16* __restrict__ xa, const __hip_bfloat16* __restrict__ wihbf,
    const float* __restrict__ bih, const float* __restrict__ bhh,
    float* __restrict__ xp)
{
  int bm = blockIdx.y;                 // 0..30
  int bn = blockIdx.x;                 // 0..7
  int w = threadIdx.x >> 6, lane = threadIdx.x & 63;
  int col = lane & 15, kg = lane >> 4;
  int m0 = bm*64;
  int n0 = bn*256 + w*64;

  f32x4 acc[4][4] = {};
  for (int kk = 0; kk < 32; kk++){
    short8 a[4], bfr[4];
    #pragma unroll
    for (int i = 0; i < 4; i++){
      a[i]   = *(const short8*)(xa    + (size_t)(m0 + i*16 + col)*1024 + kk*32 + kg*8);
      bfr[i] = *(const short8*)(wihbf + (size_t)(n0 + i*16 + col)*1024 + kk*32 + kg*8);
    }
    #pragma unroll
    for (int mt = 0; mt < 4; mt++)
      #pragma unroll
      for (int nt = 0; nt < 4; nt++)
        acc[mt][nt] = __builtin_amdgcn_mfma_f32_16x16x32_bf16(a[mt], bfr[nt], acc[mt][nt], 0, 0, 0);
  }
  float badd[4]; int ncol[4];
  #pragma unroll
  for (int nt = 0; nt < 4; nt++){ int n = n0 + nt*16 + col; ncol[nt] = n; badd[nt] = bih[n] + bhh[n]; }
  #pragma unroll
  for (int mt = 0; mt < 4; mt++)
    #pragma unroll
    for (int rg = 0; rg < 4; rg++){
      int r = m0 + mt*16 + 4*kg + rg;
      #pragma unroll
      for (int nt = 0; nt < 4; nt++)
        xp[(size_t)r*2048 + ncol[nt]] = acc[mt][nt][rg] + badd[nt];
    }
}

// ---------------------------------------------------------------------------
// Kernel 4: persistent recurrence, relaxed agent-scope atomic sync.
// 4 batch-groups (16 rows) x 32 slice-waves (16 d-cols each).
// A-operand = Whh slice (64 gate rows x K=512) persistent in 256 VGPRs.
// B-operand = h fragment. Output lane layout: (d contiguous x4, b per col-lane)
// -> h exchange is ONE u64 atomic store / lane / step, 32 u64 loads.
// No __threadfence (avoids full-L2 wb/inv); sc1 atomics + vmcnt(0) ordering.
// grid 128, block 64.
// ---------------------------------------------------------------------------
__global__ __launch_bounds__(64, 1) void k_rec(
    const __hip_bfloat16* __restrict__ whhbf,   // [2048][512]
    const float* __restrict__ xp,               // [T*64][2048]
    const float* __restrict__ enc,              // [64][512]
    const int* __restrict__ caplen,
    unsigned long long* __restrict__ hbuf,      // [2][64][512] bf16 viewed as u64
    __hip_bfloat16* __restrict__ hout,          // [64][T][512]
    unsigned* __restrict__ barr)                // 4 counters, 128 B apart
{
  const int wg = blockIdx.x;            // 0..127
  const int g = wg >> 5, s = wg & 31;   // batch-group, d-slice
  const int lane = threadIdx.x;
  const int col = lane & 15, kg = lane >> 4;
  const int d0 = s*16;
  const int b0 = g*16;
  const int b  = b0 + col;              // this lane's batch row
  const int dbase = d0 + 4*kg;          // 4 consecutive d owned by this lane

  // Persistent A fragments: Whh rows {q*512 + d0 + col}, all K=512 (256 VGPRs)
  short8 Aq[4][16];
  #pragma unroll
  for (int q = 0; q < 4; q++){
    const __hip_bfloat16* wrow = whhbf + (size_t)(q*512 + d0 + col)*512;
    #pragma unroll
    for (int kk = 0; kk < 16; kk++)
      Aq[q][kk] = *(const short8*)(wrow + kk*32 + kg*8);
  }

  // Per-lane state: (b, d = dbase+j), j=0..3
  float hst[4], cst[4];
  #pragma unroll
  for (int j = 0; j < 4; j++){
    float e = enc[(size_t)b*EE + dbase + j];
    hst[j] = e; cst[j] = e;
  }
  const int dl = caplen[b] - 1;
  unsigned* cnt = barr + g*32;

  for (int t = 0; t < TT; t++){
    // xp gate biases/projections for this step (independent of h_t; issue early)
    f32x4 xg[4];
    #pragma unroll
    for (int q = 0; q < 4; q++)
      xg[q] = *(const f32x4*)(xp + (size_t)(t*BB + b)*2048 + q*512 + dbase);

    if (t > 0){
      unsigned tgt = 32u*(unsigned)t;
      while (__hip_atomic_load(cnt, __ATOMIC_RELAXED, __HIP_MEMORY_SCOPE_AGENT) < tgt)
        __builtin_amdgcn_s_sleep(2);
      asm volatile("" ::: "memory");     // no reads of h_t hoisted above the poll
    }

    // B fragments: h_t row b, k-slice kk*32+kg*8 (2 u64 coherent loads each)
    const unsigned long long* hc = hbuf + (size_t)(t & 1)*8192;
    short8 Bf[16];
    #pragma unroll
    for (int kk = 0; kk < 16; kk++){
      union { unsigned long long u[2]; short8 v; } pack;
      size_t idx = (size_t)b*128 + kk*8 + kg*2;
      pack.u[0] = __hip_atomic_load(hc + idx,     __ATOMIC_RELAXED, __HIP_MEMORY_SCOPE_AGENT);
      pack.u[1] = __hip_atomic_load(hc + idx + 1, __ATOMIC_RELAXED, __HIP_MEMORY_SCOPE_AGENT);
      Bf[kk] = pack.v;
    }

    f32x4 acc[4] = {};
    #pragma unroll
    for (int kk = 0; kk < 16; kk++)
      #pragma unroll
      for (int q = 0; q < 4; q++)
        acc[q] = __builtin_amdgcn_mfma_f32_16x16x32_bf16(Aq[q][kk], Bf[kk], acc[q], 0, 0, 0);

    // LSTM pointwise: lane holds all 4 gates of (b, dbase+j) at acc[q][j]
    const bool act = dl > t;
    unsigned long long hpack = 0, spack = 0;
    #pragma unroll
    for (int j = 0; j < 4; j++){
      float gi = acc[0][j] + xg[0][j];
      float gf = acc[1][j] + xg[1][j];
      float gg = acc[2][j] + xg[2][j];
      float go = acc[3][j] + xg[3][j];
      float c2 = sigf(gf)*cst[j] + sigf(gi)*tanh_(gg);
      float h2 = sigf(go)*tanh_(c2);
      if (act){ cst[j] = c2; hst[j] = h2; }
      hpack |= (unsigned long long)f2bf(h2)     << (16*j);
      spack |= (unsigned long long)f2bf(hst[j]) << (16*j);
    }

    // fresh h2 -> hout (normal cached store; consumed by k_cls next kernel)
    ((unsigned long long*)hout)[((size_t)b*TT + t)*128 + (dbase >> 2)] = hpack;

    if (t < TT - 1){
      // masked state -> ping-pong buffer (coherent, no L2 flush)
      __hip_atomic_store(hbuf + (size_t)((t + 1) & 1)*8192 + (size_t)b*128 + (dbase >> 2),
                         spack, __ATOMIC_RELAXED, __HIP_MEMORY_SCOPE_AGENT);
      asm volatile("s_waitcnt vmcnt(0) lgkmcnt(0)" ::: "memory");
      if (lane == 0)
        __hip_atomic_fetch_add(cnt, 1u, __ATOMIC_RELAXED, __HIP_MEMORY_SCOPE_AGENT);
    }
  }
}

// ---------------------------------------------------------------------------
// Kernel 5: classifier GEMM fused with mask + weights broadcast.
// ---------------------------------------------------------------------------
__global__ __launch_bounds__(256) void k_cls(
    const __hip_bfloat16* __restrict__ hbf,   // [1984][512]
    const __hip_bfloat16* __restrict__ wbf,   // [10000][512]
    const float* __restrict__ clsb,
    const float* __restrict__ wgt,            // [1984], ==0 iff masked
    float* __restrict__ preds, float* __restrict__ wout)
{
  int bid = blockIdx.x;
  int bn = bid % 79, bm = bid / 79;
  int w = threadIdx.x >> 6, lane = threadIdx.x & 63;
  int col = lane & 15, kg = lane >> 4;
  int m0 = bm*128 + (w >> 1)*64;
  int n0 = bn*128 + (w & 1)*64;
  if (m0 >= 1984) return;

  int arow[4], brow[4];
  #pragma unroll
  for (int i = 0; i < 4; i++){
    arow[i] = min(m0 + i*16 + col, 1983);
    brow[i] = min(n0 + i*16 + col, 9999);
  }
  f32x4 acc[4][4] = {};
  for (int kk = 0; kk < 16; kk++){
    short8 a[4], b[4];
    #pragma unroll
    for (int i = 0; i < 4; i++){
      a[i] = *(const short8*)(hbf + (size_t)arow[i]*512 + kk*32 + kg*8);
      b[i] = *(const short8*)(wbf + (size_t)brow[i]*512 + kk*32 + kg*8);
    }
    #pragma unroll
    for (int mt = 0; mt < 4; mt++)
      #pragma unroll
      for (int nt = 0; nt < 4; nt++)
        acc[mt][nt] = __builtin_amdgcn_mfma_f32_16x16x32_bf16(a[mt], b[nt], acc[mt][nt], 0, 0, 0);
  }
  float cb[4]; int vcol[4]; bool vok[4];
  #pragma unroll
  for (int nt = 0; nt < 4; nt++){
    int v = n0 + nt*16 + col; vcol[nt] = v; vok[nt] = (v < VV);
    cb[nt] = vok[nt] ? clsb[v] : 0.f;
  }
  #pragma unroll
  for (int mt = 0; mt < 4; mt++)
    #pragma unroll
    for (int rg = 0; rg < 4; rg++){
      int r = m0 + mt*16 + 4*kg + rg;
      if (r >= 1984) continue;
      float wv = wgt[r];
      float mf = (wv > 0.f) ? 1.f : 0.f;
      size_t base = (size_t)r*VV;
      #pragma unroll
      for (int nt = 0; nt < 4; nt++){
        if (!vok[nt]) continue;
        preds[base + vcol[nt]] = (acc[mt][nt][rg] + cb[nt]) * mf;
        wout [base + vcol[nt]] = wv;
      }
    }
}

// ---------------------------------------------------------------------------
extern "C" void kernel_launch(void* const* d_in, const int* in_sizes, int n_in,
                              void* d_out, int out_size, void* d_ws, size_t ws_size,
                              hipStream_t stream) {
  const float* enc    = (const float*)d_in[0];
  const int*   cap    = (const int*)  d_in[1];
  const int*   caplen = (const int*)  d_in[2];
  const float* emb    = (const float*)d_in[3];
  const float* dwih   = (const float*)d_in[4];
  const float* dwhh   = (const float*)d_in[5];
  const float* dbih   = (const float*)d_in[6];
  const float* dbhh   = (const float*)d_in[7];
  const float* wwih   = (const float*)d_in[8];
  const float* wwhh   = (const float*)d_in[9];
  const float* wbih   = (const float*)d_in[10];
  const float* wbhh   = (const float*)d_in[11];
  const float* ihw    = (const float*)d_in[12];
  const float* ihb    = (const float*)d_in[13];
  const float* icw    = (const float*)d_in[14];
  const float* icb    = (const float*)d_in[15];
  const float* clsw   = (const float*)d_in[16];
  const float* clsb   = (const float*)d_in[17];

  float* preds  = (float*)d_out;                       // [64][31][10000]
  float* dl_out = preds + (size_t)BB*TT*VV;            // [64]
  float* wout   = dl_out + BB;                         // [64][31][10000]

  char* ws = (char*)d_ws;
  float*          wgt   = (float*)         (ws + 0);          // 1984 f32   (pad 8192)
  unsigned*       barr  = (unsigned*)      (ws + 8192);       // 128 u32    (pad 512)
  __hip_bfloat16* clsbf = (__hip_bfloat16*)(ws + 8704);       // 10,240,000 B
  __hip_bfloat16* wihbf = (__hip_bfloat16*)(ws + 10248704);   //  4,194,304 B
  __hip_bfloat16* whhbf = (__hip_bfloat16*)(ws + 14443008);   //  2,097,152 B
  __hip_bfloat16* xa    = (__hip_bfloat16*)(ws + 16540160);   //  4,063,232 B
  float*          xp    = (float*)         (ws + 20603392);   // 16,252,928 B
  __hip_bfloat16* hbuf  = (__hip_bfloat16*)(ws + 36856320);   //    131,072 B
  __hip_bfloat16* hout  = (__hip_bfloat16*)(ws + 36987392);   //  2,031,616 B

  k_wlstm<<<BB, 256, 0, stream>>>(enc, caplen, wwih, wwhh, wbih, wbhh,
                                  ihw, ihb, icw, icb, wgt, barr, dl_out);
  k_prep <<<4096, 256, 0, stream>>>(clsw, dwih, dwhh, emb, cap, enc,
                                    clsbf, wihbf, whhbf, xa, hbuf);
  k_xproj<<<dim3(8, 31), 256, 0, stream>>>(xa, wihbf, dbih, dbhh, xp);
  k_rec  <<<128, 64, 0, stream>>>(whhbf, xp, enc, caplen,
                                  (unsigned long long*)hbuf, hout, barr);
  k_cls  <<<16*79, 256, 0, stream>>>(hout, clsbf, clsb, wgt, preds, wout);
}